// Round 3
// baseline (476.791 us; speedup 1.0000x reference)
//
#include <hip/hip_runtime.h>
#include <hip/hip_bf16.h>

typedef __bf16 bf16_t;
typedef __bf16 bf16x8 __attribute__((ext_vector_type(8)));
typedef float  f32x4  __attribute__((ext_vector_type(4)));

#define MFMA16(A,B,C) __builtin_amdgcn_mfma_f32_16x16x32_bf16(A,B,C,0,0,0)

constexpr int HIDc = 4544;
constexpr int NHc  = 71;
constexpr int NHPc = 80;   // padded head count
constexpr int HDc  = 64;
constexpr int Uc   = 32;
constexpr int Sc   = 2048;
constexpr int NPBc = 8;    // flash partial blocks per user (1024 keys each)

// ---- workspace layout (bytes) ----
constexpr size_t OFF_QHI  = 0;                       // [32][80][64] bf16
constexpr size_t OFF_QLO  = 327680;
constexpr size_t OFF_KCUR = 655360;                  // [32][64] f32
constexpr size_t OFF_VCUR = 663552;                  // [32][64] f32
constexpr size_t OFF_MP   = 671744;                  // [32][8][71] f32
constexpr size_t OFF_LP   = 744448;
constexpr size_t OFF_OP   = 817152;                  // [32][8][71][64] f32
constexpr size_t OFF_AHI  = 5470208;                 // [32][4544] bf16
constexpr size_t OFF_ALO  = 5761024;
constexpr size_t OFF_FLAG = 6051840;                 // int dtype flag
constexpr size_t WS_NEED  = 6051904;

// ---------------- dtype probe ----------------
// w_qkv ~ 0.02*N(0,1). As bf16 data: no u16 word has bf16 exponent >= 128
// (would mean |w| >= 2). As fp32 data: every other u16 is a random mantissa
// word -> ~25-50% have exponent >= 128. flag=1 => inputs are float32.
__global__ void k_detect(const unsigned short* __restrict__ w, int* __restrict__ flag) {
  __shared__ int cnt;
  if (threadIdx.x == 0) cnt = 0;
  __syncthreads();
  int c = 0;
  for (int i = threadIdx.x; i < 8192; i += 256) {
    const int e = (w[i] >> 7) & 0xff;
    c += (e >= 128) ? 1 : 0;
  }
  atomicAdd(&cnt, c);
  __syncthreads();
  if (threadIdx.x == 0) *flag = (cnt > 512) ? 1 : 0;
}

// ---------------- typed load helpers ----------------
template<bool F32>
__device__ __forceinline__ bf16x8 ld8(const void* base, long eidx) {
  if constexpr (F32) {
    const float* p = (const float*)base + eidx;
    const f32x4 a = *(const f32x4*)p;
    const f32x4 b = *(const f32x4*)(p + 4);
    bf16x8 r;
    r[0]=(bf16_t)a[0]; r[1]=(bf16_t)a[1]; r[2]=(bf16_t)a[2]; r[3]=(bf16_t)a[3];
    r[4]=(bf16_t)b[0]; r[5]=(bf16_t)b[1]; r[6]=(bf16_t)b[2]; r[7]=(bf16_t)b[3];
    return r;
  } else {
    return *(const bf16x8*)((const bf16_t*)base + eidx);
  }
}
template<bool F32>
__device__ __forceinline__ float ldf(const void* base, long eidx) {
  if constexpr (F32) return ((const float*)base)[eidx];
  else               return (float)((const bf16_t*)base)[eidx];
}

// ---------------- Kernel 1: fused QKV GEMM + rotary ----------------
template<bool F32>
__device__ __forceinline__ void qkvrot_body(
    const void* hidden, const void* wqkv, const void* cosp, const void* sinp,
    bf16_t* qhi, bf16_t* qlo, float* kcur, float* vcur,
    const int h, const int t, float* sD)
{
  if (h < 73) {
    const int wave = t >> 6, lane = t & 63;
    const int c = lane & 15, q4 = lane >> 4;
    const int mt = wave & 1, kq = wave >> 1;
    const long k0 = (long)kq * 2272;
    const long abase = (long)(mt*16 + c)*HIDc + k0 + q4*8;
    const long bbase = ((long)h*64 + c)*HIDc  + k0 + q4*8;
    f32x4 acc[4] = {};
#pragma unroll 4
    for (int ks = 0; ks < 71; ++ks) {
      const bf16x8 af = ld8<F32>(hidden, abase + ks*32);
#pragma unroll
      for (int nf = 0; nf < 4; ++nf) {
        const bf16x8 bv = ld8<F32>(wqkv, bbase + (long)nf*16*HIDc + ks*32);
        acc[nf] = MFMA16(af, bv, acc[nf]);
      }
    }
    if (kq == 0) {
#pragma unroll
      for (int r = 0; r < 4; ++r)
#pragma unroll
        for (int nf = 0; nf < 4; ++nf)
          sD[(mt*16 + q4*4 + r)*64 + nf*16 + c] = acc[nf][r];
    }
    __syncthreads();
    if (kq == 1) {
#pragma unroll
      for (int r = 0; r < 4; ++r)
#pragma unroll
        for (int nf = 0; nf < 4; ++nf)
          sD[(mt*16 + q4*4 + r)*64 + nf*16 + c] += acc[nf][r];
    }
    __syncthreads();
  }
  if (h >= NHc) {  // zero q pad rows 71..79
    for (int i = t; i < Uc*HDc; i += 256) {
      const long idx = (((long)(i >> 6))*NHPc + h)*HDc + (i & 63);
      qhi[idx] = (bf16_t)0.f;  qlo[idx] = (bf16_t)0.f;
    }
  }
  if (h >= 73) return;
  for (int i = t; i < Uc*HDc; i += 256) {
    const int u = i >> 6, d = i & 63;
    const float x = sD[i];
    const float partner = sD[i ^ 32];
    const float cs = ldf<F32>(cosp, u*HDc + d);
    const float sn = ldf<F32>(sinp, u*HDc + d);
    const float rh = (d < 32) ? -partner : partner;
    const float val = x*cs + rh*sn;
    if (h < NHc) {
      const long idx = ((long)u*NHPc + h)*HDc + d;
      const bf16_t hi = (bf16_t)val;
      qhi[idx] = hi;
      qlo[idx] = (bf16_t)(val - (float)hi);
    } else if (h == NHc) {
      kcur[u*HDc + d] = val;     // rotated shared K head
    } else {
      vcur[u*HDc + d] = x;       // V head: no rotary
    }
  }
}

__global__ __launch_bounds__(256) void k_qkvrot(
    const void* hidden, const void* wqkv, const void* cosp, const void* sinp,
    bf16_t* qhi, bf16_t* qlo, float* kcur, float* vcur, const int* flag)
{
  __shared__ float sD[Uc*HDc];
  const int h = blockIdx.x, t = threadIdx.x;
  if (*flag) qkvrot_body<true >(hidden, wqkv, cosp, sinp, qhi, qlo, kcur, vcur, h, t, sD);
  else       qkvrot_body<false>(hidden, wqkv, cosp, sinp, qhi, qlo, kcur, vcur, h, t, sD);
}

// ---------------- Kernel 2: flash-decode partials ----------------
template<bool F32>
__device__ __forceinline__ void attn_body(
    const void* kc, const void* vc, const void* masks,
    const bf16_t* qhi, const bf16_t* qlo,
    float* Mp, float* Lp, float* Op,
    const int u, const int pb, const int tid,
    float (*sM)[NHPc], float (*sL)[NHPc], float* sO)
{
  const int wave = tid >> 6;
  const int lane = tid & 63;
  const int c    = lane & 15;
  const int q4   = lane >> 4;
  const int chunk  = pb >> 1;
  const int s_base = (pb & 1)*1024 + wave*256;
  const long kvbase = ((long)(chunk*Uc + u))*Sc;

  // Q B-fragments (hi/lo): B[k=d][n=head]  (internal, always bf16)
  bf16x8 qh[5][2], ql[5][2];
  const bf16_t* qb  = qhi + ((long)u*NHPc + c)*HDc + q4*8;
  const bf16_t* qb2 = qlo + ((long)u*NHPc + c)*HDc + q4*8;
#pragma unroll
  for (int ht = 0; ht < 5; ++ht)
#pragma unroll
    for (int ks = 0; ks < 2; ++ks) {
      qh[ht][ks] = *(const bf16x8*)(qb  + ht*16*HDc + ks*32);
      ql[ht][ks] = *(const bf16x8*)(qb2 + ht*16*HDc + ks*32);
    }

  float m_i[5], l_i[5];
  f32x4 Oa[5][4] = {};
#pragma unroll
  for (int ht = 0; ht < 5; ++ht) { m_i[ht] = -INFINITY; l_i[ht] = 0.f; }

  for (int t = 0; t < 8; ++t) {
    const int s0 = s_base + t*32;
    // K A-fragments: A[m=key][k=d]
    bf16x8 kf[2][2];
#pragma unroll
    for (int mt2 = 0; mt2 < 2; ++mt2)
#pragma unroll
      for (int ks = 0; ks < 2; ++ks)
        kf[mt2][ks] = ld8<F32>(kc, (kvbase + s0 + mt2*16 + c)*HDc + ks*32 + q4*8);

    // S^T = K * Q^T  (row=key, col=head)
    f32x4 S[2][5];
#pragma unroll
    for (int mt2 = 0; mt2 < 2; ++mt2)
#pragma unroll
      for (int ht = 0; ht < 5; ++ht) {
        f32x4 s = {};
        s = MFMA16(kf[mt2][0], qh[ht][0], s);
        s = MFMA16(kf[mt2][1], qh[ht][1], s);
        s = MFMA16(kf[mt2][0], ql[ht][0], s);
        s = MFMA16(kf[mt2][1], ql[ht][1], s);
        S[mt2][ht] = s;
      }

    // scale + mask (mask depends only on key row)
    float mk[2][4];
#pragma unroll
    for (int mt2 = 0; mt2 < 2; ++mt2)
#pragma unroll
      for (int r = 0; r < 4; ++r)
        mk[mt2][r] = ldf<F32>(masks, kvbase + s0 + q4*4 + mt2*16 + r);
#pragma unroll
    for (int mt2 = 0; mt2 < 2; ++mt2)
#pragma unroll
      for (int ht = 0; ht < 5; ++ht)
#pragma unroll
        for (int r = 0; r < 4; ++r)
          S[mt2][ht][r] = S[mt2][ht][r]*0.125f + mk[mt2][r];

    // online softmax (per head = lane&15 within tile ht)
    float alpha[5];
#pragma unroll
    for (int ht = 0; ht < 5; ++ht) {
      float tm = S[0][ht][0];
#pragma unroll
      for (int mt2 = 0; mt2 < 2; ++mt2)
#pragma unroll
        for (int r = 0; r < 4; ++r) tm = fmaxf(tm, S[mt2][ht][r]);
      tm = fmaxf(tm, __shfl_xor(tm, 16));
      tm = fmaxf(tm, __shfl_xor(tm, 32));
      const float mn = fmaxf(m_i[ht], tm);
      alpha[ht] = __expf(m_i[ht] - mn);
      m_i[ht] = mn;
    }
#pragma unroll
    for (int mt2 = 0; mt2 < 2; ++mt2)
#pragma unroll
      for (int ht = 0; ht < 5; ++ht)
#pragma unroll
        for (int r = 0; r < 4; ++r)
          S[mt2][ht][r] = __expf(S[mt2][ht][r] - m_i[ht]);
#pragma unroll
    for (int ht = 0; ht < 5; ++ht) {
      float rs = 0.f;
#pragma unroll
      for (int mt2 = 0; mt2 < 2; ++mt2)
#pragma unroll
        for (int r = 0; r < 4; ++r) rs += S[mt2][ht][r];
      rs += __shfl_xor(rs, 16);
      rs += __shfl_xor(rs, 32);
      l_i[ht] = l_i[ht]*alpha[ht] + rs;
    }
    // rescale O (O row head = q4*4+r; alpha lives on lane&15=head)
#pragma unroll
    for (int ht = 0; ht < 5; ++ht)
#pragma unroll
      for (int r = 0; r < 4; ++r) {
        const float ar = __shfl(alpha[ht], q4*4 + r);
#pragma unroll
        for (int dt = 0; dt < 4; ++dt) Oa[ht][dt][r] *= ar;
      }
    // P -> A-operand layout (hi/lo), via quad shuffles
    bf16x8 ph[5], pl[5];
#pragma unroll
    for (int ht = 0; ht < 5; ++ht) {
      union { bf16_t e[8]; bf16x8 v; } uh, ul;
#pragma unroll
      for (int j = 0; j < 8; ++j) {
        const int src = (((2*q4 + (j>>2)) & 3) << 4) + c;
        const float v0 = __shfl(S[0][ht][j & 3], src);
        const float v1 = __shfl(S[1][ht][j & 3], src);
        const float val = (q4 < 2) ? v0 : v1;
        const bf16_t hi = (bf16_t)val;
        uh.e[j] = hi;
        ul.e[j] = (bf16_t)(val - (float)hi);
      }
      ph[ht] = uh.v;  pl[ht] = ul.v;
    }
    // V B-fragments: B[k=key][n=dim]
    bf16x8 vf[4];
#pragma unroll
    for (int dt = 0; dt < 4; ++dt) {
      union { bf16_t e[8]; bf16x8 v; } uv;
#pragma unroll
      for (int j = 0; j < 8; ++j)
        uv.e[j] = (bf16_t)ldf<F32>(vc, (kvbase + s0 + q4*8 + j)*HDc + dt*16 + c);
      vf[dt] = uv.v;
    }
#pragma unroll
    for (int ht = 0; ht < 5; ++ht)
#pragma unroll
      for (int dt = 0; dt < 4; ++dt) {
        Oa[ht][dt] = MFMA16(ph[ht], vf[dt], Oa[ht][dt]);
        Oa[ht][dt] = MFMA16(pl[ht], vf[dt], Oa[ht][dt]);
      }
  }

  // ---- block-level combine of the 4 wave segments ----
  if (lane < 16)
#pragma unroll
    for (int ht = 0; ht < 5; ++ht) {
      sM[wave][ht*16 + lane] = m_i[ht];
      sL[wave][ht*16 + lane] = l_i[ht];
    }
  __syncthreads();
#pragma unroll
  for (int ht = 0; ht < 5; ++ht)
#pragma unroll
    for (int r = 0; r < 4; ++r) {
      const int hh = ht*16 + q4*4 + r;
      float mg = fmaxf(fmaxf(sM[0][hh], sM[1][hh]), fmaxf(sM[2][hh], sM[3][hh]));
      mg = fmaxf(mg, -1e30f);
      const float aw = __expf(sM[wave][hh] - mg);
#pragma unroll
      for (int dt = 0; dt < 4; ++dt) Oa[ht][dt][r] *= aw;
    }
  for (int w = 0; w < 4; ++w) {
    if (wave == w) {
#pragma unroll
      for (int ht = 0; ht < 5; ++ht)
#pragma unroll
        for (int dt = 0; dt < 4; ++dt)
#pragma unroll
          for (int r = 0; r < 4; ++r) {
            const int idx = (ht*16 + q4*4 + r)*HDc + dt*16 + c;
            if (w == 0) sO[idx] = Oa[ht][dt][r];
            else        sO[idx] += Oa[ht][dt][r];
          }
    }
    __syncthreads();
  }
  float* op = Op + ((long)u*NPBc + pb)*NHc*HDc;
  for (int i = tid; i < NHc*HDc; i += 256) op[i] = sO[i];
  if (wave == 0 && lane < 16) {
#pragma unroll
    for (int ht = 0; ht < 5; ++ht) {
      const int hh = ht*16 + lane;
      if (hh < NHc) {
        float mg = fmaxf(fmaxf(sM[0][hh], sM[1][hh]), fmaxf(sM[2][hh], sM[3][hh]));
        mg = fmaxf(mg, -1e30f);
        float L = 0.f;
#pragma unroll
        for (int w = 0; w < 4; ++w) L += __expf(sM[w][hh] - mg)*sL[w][hh];
        Mp[((long)u*NPBc + pb)*NHc + hh] = mg;
        Lp[((long)u*NPBc + pb)*NHc + hh] = L;
      }
    }
  }
}

__global__ __launch_bounds__(256, 1) void k_attn(
    const void* kc, const void* vc, const void* masks,
    const bf16_t* qhi, const bf16_t* qlo,
    float* Mp, float* Lp, float* Op, const int* flag)
{
  __shared__ float sM[4][NHPc], sL[4][NHPc];
  __shared__ float sO[NHPc*HDc];
  const int u = blockIdx.x, pb = blockIdx.y, tid = threadIdx.x;
  if (*flag) attn_body<true >(kc, vc, masks, qhi, qlo, Mp, Lp, Op, u, pb, tid, sM, sL, sO);
  else       attn_body<false>(kc, vc, masks, qhi, qlo, Mp, Lp, Op, u, pb, tid, sM, sL, sO);
}

// ---------------- Kernel 3: combine partials + current token ----------------
// (all operands internal -> dtype-independent)
__global__ __launch_bounds__(64) void k_combine(
    const float* __restrict__ Mp, const float* __restrict__ Lp,
    const float* __restrict__ Op,
    const bf16_t* __restrict__ qhi, const bf16_t* __restrict__ qlo,
    const float* __restrict__ kcur, const float* __restrict__ vcur,
    bf16_t* __restrict__ ahi, bf16_t* __restrict__ alo)
{
  const int h = blockIdx.x, u = blockIdx.y;
  const int lane = threadIdx.x;   // = d
  const long qidx = ((long)u*NHPc + h)*HDc + lane;
  float pr = ((float)qhi[qidx] + (float)qlo[qidx]) * kcur[u*HDc + lane];
#pragma unroll
  for (int o = 32; o > 0; o >>= 1) pr += __shfl_xor(pr, o);
  const float s_cur = pr * 0.125f;

  float mp[NPBc], lp[NPBc];
  float g = s_cur;
#pragma unroll
  for (int p = 0; p < NPBc; ++p) {
    mp[p] = Mp[((long)u*NPBc + p)*NHc + h];
    lp[p] = Lp[((long)u*NPBc + p)*NHc + h];
    g = fmaxf(g, mp[p]);
  }
  g = fmaxf(g, -1e30f);
  float sw = 0.f, acc = 0.f;
  const float* ob = Op + ((long)u*NPBc)*NHc*HDc + (long)h*HDc + lane;
#pragma unroll
  for (int p = 0; p < NPBc; ++p) {
    const float f = __expf(mp[p] - g);
    sw += f*lp[p];
    acc += f*ob[(long)p*NHc*HDc];
  }
  const float cw = __expf(s_cur - g);
  acc += cw * vcur[u*HDc + lane];
  const float attn = acc / (sw + cw);
  const bf16_t hi = (bf16_t)attn;
  ahi[(long)u*HIDc + h*HDc + lane] = hi;
  alo[(long)u*HIDc + h*HDc + lane] = (bf16_t)(attn - (float)hi);
}

// ---------------- Kernel 4: dense GEMM, K-split reduced in LDS ----------------
template<bool F32>
__device__ __forceinline__ void outgemm_body(
    const bf16_t* ahi, const bf16_t* alo, const void* wd, void* out,
    const int nb, const int t, float* sC)
{
  const int wave = t >> 6, lane = t & 63;
  const int c = lane & 15, q4 = lane >> 4;
  const int mt = wave & 1, kq = wave >> 1;
  const long k0 = (long)kq * 2272;

  const bf16_t* aph = ahi + ((long)(mt*16 + c))*HIDc + k0 + q4*8;
  const bf16_t* apl = alo + ((long)(mt*16 + c))*HIDc + k0 + q4*8;
  const long bbase = ((long)nb*32 + c)*HIDc + k0 + q4*8;

  f32x4 acc[2] = {};
#pragma unroll 4
  for (int ks = 0; ks < 71; ++ks) {
    const bf16x8 Ah = *(const bf16x8*)(aph + ks*32);
    const bf16x8 Al = *(const bf16x8*)(apl + ks*32);
#pragma unroll
    for (int nf = 0; nf < 2; ++nf) {
      const bf16x8 B = ld8<F32>(wd, bbase + (long)nf*16*HIDc + ks*32);
      acc[nf] = MFMA16(Ah, B, acc[nf]);
      acc[nf] = MFMA16(Al, B, acc[nf]);
    }
  }
  if (kq == 0) {
#pragma unroll
    for (int r = 0; r < 4; ++r)
#pragma unroll
      for (int nf = 0; nf < 2; ++nf)
        sC[(mt*16 + q4*4 + r)*32 + nf*16 + c] = acc[nf][r];
  }
  __syncthreads();
  if (kq == 1) {
#pragma unroll
    for (int r = 0; r < 4; ++r)
#pragma unroll
      for (int nf = 0; nf < 2; ++nf)
        sC[(mt*16 + q4*4 + r)*32 + nf*16 + c] += acc[nf][r];
  }
  __syncthreads();
  for (int i = t; i < Uc*32; i += 256) {
    const int u = i >> 5, col = i & 31;
    const long oidx = (long)u*HIDc + nb*32 + col;
    if constexpr (F32) ((float*)out)[oidx] = sC[i];
    else               ((bf16_t*)out)[oidx] = (bf16_t)sC[i];
  }
}

__global__ __launch_bounds__(256) void k_outgemm(
    const bf16_t* ahi, const bf16_t* alo, const void* wd, void* out, const int* flag)
{
  __shared__ float sC[Uc*32];
  const int nb = blockIdx.x, t = threadIdx.x;
  if (*flag) outgemm_body<true >(ahi, alo, wd, out, nb, t, sC);
  else       outgemm_body<false>(ahi, alo, wd, out, nb, t, sC);
}

extern "C" void kernel_launch(void* const* d_in, const int* in_sizes, int n_in,
                              void* d_out, int out_size, void* d_ws, size_t ws_size,
                              hipStream_t stream)
{
  const void* hidden = d_in[0];
  const void* cosp   = d_in[1];
  const void* sinp   = d_in[2];
  const void* kcache = d_in[3];
  const void* vcache = d_in[4];
  const void* masks  = d_in[5];
  const void* wqkv   = d_in[6];
  const void* wdense = d_in[7];

  if (ws_size < WS_NEED) return;  // harness pre-memsets d_out -> zero signature

  char* ws = (char*)d_ws;
  bf16_t* qhi  = (bf16_t*)(ws + OFF_QHI);
  bf16_t* qlo  = (bf16_t*)(ws + OFF_QLO);
  float*  kcur = (float*)(ws + OFF_KCUR);
  float*  vcur = (float*)(ws + OFF_VCUR);
  float*  Mp   = (float*)(ws + OFF_MP);
  float*  Lp   = (float*)(ws + OFF_LP);
  float*  Op   = (float*)(ws + OFF_OP);
  bf16_t* ahi  = (bf16_t*)(ws + OFF_AHI);
  bf16_t* alo  = (bf16_t*)(ws + OFF_ALO);
  int*    flag = (int*)(ws + OFF_FLAG);

  k_detect <<<1, 256, 0, stream>>>((const unsigned short*)wqkv, flag);
  k_qkvrot <<<80, 256, 0, stream>>>(hidden, wqkv, cosp, sinp, qhi, qlo, kcur, vcur, flag);
  k_attn   <<<dim3(32, 8), 256, 0, stream>>>(kcache, vcache, masks, qhi, qlo, Mp, Lp, Op, flag);
  k_combine<<<dim3(71, 32), 64, 0, stream>>>(Mp, Lp, Op, qhi, qlo, kcur, vcur, ahi, alo);
  k_outgemm<<<142, 256, 0, stream>>>(ahi, alo, wdense, d_out, flag);
}

// Round 4
// 359.786 us; speedup vs baseline: 1.3252x; 1.3252x over previous
//
#include <hip/hip_runtime.h>
#include <hip/hip_bf16.h>

typedef __bf16 bf16_t;
typedef __bf16 bf16x8 __attribute__((ext_vector_type(8)));
typedef float  f32x4  __attribute__((ext_vector_type(4)));

#define MFMA16(A,B,C) __builtin_amdgcn_mfma_f32_16x16x32_bf16(A,B,C,0,0,0)

constexpr int HIDc = 4544;   // 142 k-steps of 32
constexpr int NHc  = 71;
constexpr int NHPc = 80;
constexpr int HDc  = 64;
constexpr int Uc   = 32;
constexpr int Sc   = 2048;
constexpr int RQ   = 4672;   // (71+2)*64

// ---- workspace layout (bytes) ----
constexpr size_t OFF_FUSED = 0;           // [32][4672] f32 = 598016
constexpr size_t OFF_QHI   = 598016;      // [32][80][64] bf16
constexpr size_t OFF_QLO   = 925696;
constexpr size_t OFF_KCUR  = 1253376;     // [32][64] f32
constexpr size_t OFF_VCUR  = 1261568;
constexpr size_t OFF_MP    = 1269760;     // [32][NPB<=16][71] f32 (max 145408)
constexpr size_t OFF_LP    = 1415168;
constexpr size_t OFF_AHI   = 1560576;     // [32][4544] bf16
constexpr size_t OFF_ALO   = 1851392;
constexpr size_t OFF_OP    = 2142208;     // [32][NPB][71][64] f32

// fp32 -> bf16x8 load (32B aligned)
__device__ __forceinline__ bf16x8 ld8f(const float* base, long eidx) {
  const float* p = base + eidx;
  const f32x4 a = *(const f32x4*)p;
  const f32x4 b = *(const f32x4*)(p + 4);
  bf16x8 r;
  r[0]=(bf16_t)a[0]; r[1]=(bf16_t)a[1]; r[2]=(bf16_t)a[2]; r[3]=(bf16_t)a[3];
  r[4]=(bf16_t)b[0]; r[5]=(bf16_t)b[1]; r[6]=(bf16_t)b[2]; r[7]=(bf16_t)b[3];
  return r;
}

// ---------------- zero fused + d_out ----------------
__global__ __launch_bounds__(256) void k_zeros(float* fused, float* out) {
  const int i = blockIdx.x*256 + threadIdx.x;       // grid 1152 -> 294912
  if (i < Uc*RQ) fused[i] = 0.f;
  else           out[i - Uc*RQ] = 0.f;              // Uc*HIDc elements
}

// ---------------- Kernel 1: QKV GEMM, grid (73,8), atomic reduce ----------------
__global__ __launch_bounds__(256) void k_qkv(
    const float* __restrict__ hidden, const float* __restrict__ wqkv,
    float* __restrict__ fused)
{
  const int h = blockIdx.x, y = blockIdx.y;
  const int t = threadIdx.x;
  const int wave = t >> 6, lane = t & 63;
  const int c = lane & 15, q4 = lane >> 4;
  const int mt = wave & 1, kh = wave >> 1;
  const int ks0 = y*18;
  const int ksn = min(18, 142 - ks0);     // y=7 gets 16
  const int h1  = ksn >> 1;
  const int kbeg = ks0 + (kh ? h1 : 0);
  const int kend = ks0 + (kh ? ksn : h1);
  __shared__ float sD[Uc*HDc];

  const long abase = (long)(mt*16 + c)*HIDc + q4*8;
  const long bbase = ((long)h*64 + c)*HIDc + q4*8;
  f32x4 acc[4] = {};
#pragma unroll 3
  for (int ks = kbeg; ks < kend; ++ks) {
    const bf16x8 af = ld8f(hidden, abase + ks*32);
#pragma unroll
    for (int nf = 0; nf < 4; ++nf) {
      const bf16x8 bv = ld8f(wqkv, bbase + (long)nf*16*HIDc + ks*32);
      acc[nf] = MFMA16(af, bv, acc[nf]);
    }
  }
  if (kh == 0) {
#pragma unroll
    for (int r = 0; r < 4; ++r)
#pragma unroll
      for (int nf = 0; nf < 4; ++nf)
        sD[(mt*16 + q4*4 + r)*64 + nf*16 + c] = acc[nf][r];
  }
  __syncthreads();
  if (kh == 1) {
#pragma unroll
    for (int r = 0; r < 4; ++r)
#pragma unroll
      for (int nf = 0; nf < 4; ++nf)
        sD[(mt*16 + q4*4 + r)*64 + nf*16 + c] += acc[nf][r];
  }
  __syncthreads();
  for (int i = t; i < Uc*HDc; i += 256)
    atomicAdd(&fused[(long)(i >> 6)*RQ + h*64 + (i & 63)], sD[i]);
}

// ---------------- Kernel 2: rotary + hi/lo split ----------------
__global__ __launch_bounds__(256) void k_rotary(
    const float* __restrict__ fused,
    const float* __restrict__ cosp, const float* __restrict__ sinp,
    bf16_t* __restrict__ qhi, bf16_t* __restrict__ qlo,
    float* __restrict__ kcur, float* __restrict__ vcur)
{
  const int h = blockIdx.x;    // 0..79
  const int t = threadIdx.x;
  __shared__ float sD[Uc*HDc];
  if (h < 73) {
    for (int i = t; i < Uc*HDc; i += 256)
      sD[i] = fused[(long)(i >> 6)*RQ + h*64 + (i & 63)];
    __syncthreads();
  }
  if (h >= NHc) {  // zero q pad rows 71..79
    for (int i = t; i < Uc*HDc; i += 256) {
      const long idx = (((long)(i >> 6))*NHPc + h)*HDc + (i & 63);
      qhi[idx] = (bf16_t)0.f;  qlo[idx] = (bf16_t)0.f;
    }
  }
  if (h >= 73) return;
  for (int i = t; i < Uc*HDc; i += 256) {
    const int u = i >> 6, d = i & 63;
    const float x = sD[i];
    const float partner = sD[i ^ 32];
    const float cs = cosp[u*HDc + d];
    const float sn = sinp[u*HDc + d];
    const float rh = (d < 32) ? -partner : partner;
    const float val = x*cs + rh*sn;
    if (h < NHc) {
      const long idx = ((long)u*NHPc + h)*HDc + d;
      const bf16_t hi = (bf16_t)val;
      qhi[idx] = hi;
      qlo[idx] = (bf16_t)(val - (float)hi);
    } else if (h == NHc) {
      kcur[u*HDc + d] = val;     // rotated shared K head
    } else {
      vcur[u*HDc + d] = x;       // V head: no rotary
    }
  }
}

// ---------------- Kernel 3: flash-decode partials, grid (32, NPB) ----------------
__global__ __launch_bounds__(256, 1) void k_attn(
    const float* __restrict__ kc, const float* __restrict__ vc,
    const float* __restrict__ masks,
    const bf16_t* __restrict__ qhi, const bf16_t* __restrict__ qlo,
    float* __restrict__ Mp, float* __restrict__ Lp, float* __restrict__ Op,
    const int NPB)
{
  __shared__ float sM[4][NHPc], sL[4][NHPc];
  __shared__ float sO[NHPc*HDc];
  const int u  = blockIdx.x;
  const int pb = blockIdx.y;
  const int tid = threadIdx.x;
  const int wave = tid >> 6;
  const int lane = tid & 63;
  const int c    = lane & 15;
  const int q4   = lane >> 4;
  const int pbpc = NPB >> 2;            // partial blocks per chunk
  const int keys_pb   = 2048 / pbpc;
  const int keys_wave = keys_pb >> 2;
  const int tcnt      = keys_wave >> 5;
  const int chunk = pb / pbpc;
  const int inner = pb - chunk*pbpc;
  const int s_base = inner*keys_pb + wave*keys_wave;
  const long kvbase = ((long)(chunk*Uc + u))*Sc;

  // Q B-fragments (hi/lo): B[k=d][n=head]
  bf16x8 qh[5][2], ql[5][2];
  const bf16_t* qb  = qhi + ((long)u*NHPc + c)*HDc + q4*8;
  const bf16_t* qb2 = qlo + ((long)u*NHPc + c)*HDc + q4*8;
#pragma unroll
  for (int ht = 0; ht < 5; ++ht)
#pragma unroll
    for (int ks = 0; ks < 2; ++ks) {
      qh[ht][ks] = *(const bf16x8*)(qb  + ht*16*HDc + ks*32);
      ql[ht][ks] = *(const bf16x8*)(qb2 + ht*16*HDc + ks*32);
    }

  float m_i[5], l_i[5];
  f32x4 Oa[5][4] = {};
#pragma unroll
  for (int ht = 0; ht < 5; ++ht) { m_i[ht] = -INFINITY; l_i[ht] = 0.f; }

  for (int t = 0; t < tcnt; ++t) {
    const int s0 = s_base + t*32;
    // K A-fragments: A[m=key][k=d]
    bf16x8 kf[2][2];
#pragma unroll
    for (int mt2 = 0; mt2 < 2; ++mt2)
#pragma unroll
      for (int ks = 0; ks < 2; ++ks)
        kf[mt2][ks] = ld8f(kc, (kvbase + s0 + mt2*16 + c)*HDc + ks*32 + q4*8);

    // S^T = K * Q^T  (row=key, col=head)
    f32x4 S[2][5];
#pragma unroll
    for (int mt2 = 0; mt2 < 2; ++mt2)
#pragma unroll
      for (int ht = 0; ht < 5; ++ht) {
        f32x4 s = {};
        s = MFMA16(kf[mt2][0], qh[ht][0], s);
        s = MFMA16(kf[mt2][1], qh[ht][1], s);
        s = MFMA16(kf[mt2][0], ql[ht][0], s);
        s = MFMA16(kf[mt2][1], ql[ht][1], s);
        S[mt2][ht] = s;
      }

    // scale + mask (mask depends only on key row)
    float mk[2][4];
#pragma unroll
    for (int mt2 = 0; mt2 < 2; ++mt2)
#pragma unroll
      for (int r = 0; r < 4; ++r)
        mk[mt2][r] = masks[kvbase + s0 + q4*4 + mt2*16 + r];
#pragma unroll
    for (int mt2 = 0; mt2 < 2; ++mt2)
#pragma unroll
      for (int ht = 0; ht < 5; ++ht)
#pragma unroll
        for (int r = 0; r < 4; ++r)
          S[mt2][ht][r] = S[mt2][ht][r]*0.125f + mk[mt2][r];

    // online softmax (head = lane&15 within tile ht)
    float alpha[5];
#pragma unroll
    for (int ht = 0; ht < 5; ++ht) {
      float tm = S[0][ht][0];
#pragma unroll
      for (int mt2 = 0; mt2 < 2; ++mt2)
#pragma unroll
        for (int r = 0; r < 4; ++r) tm = fmaxf(tm, S[mt2][ht][r]);
      tm = fmaxf(tm, __shfl_xor(tm, 16));
      tm = fmaxf(tm, __shfl_xor(tm, 32));
      const float mn = fmaxf(m_i[ht], tm);
      alpha[ht] = __expf(m_i[ht] - mn);
      m_i[ht] = mn;
    }
#pragma unroll
    for (int mt2 = 0; mt2 < 2; ++mt2)
#pragma unroll
      for (int ht = 0; ht < 5; ++ht)
#pragma unroll
        for (int r = 0; r < 4; ++r)
          S[mt2][ht][r] = __expf(S[mt2][ht][r] - m_i[ht]);
#pragma unroll
    for (int ht = 0; ht < 5; ++ht) {
      float rs = 0.f;
#pragma unroll
      for (int mt2 = 0; mt2 < 2; ++mt2)
#pragma unroll
        for (int r = 0; r < 4; ++r) rs += S[mt2][ht][r];
      rs += __shfl_xor(rs, 16);
      rs += __shfl_xor(rs, 32);
      l_i[ht] = l_i[ht]*alpha[ht] + rs;
    }
    // rescale O (O row head = q4*4+r)
#pragma unroll
    for (int ht = 0; ht < 5; ++ht)
#pragma unroll
      for (int r = 0; r < 4; ++r) {
        const float ar = __shfl(alpha[ht], q4*4 + r);
#pragma unroll
        for (int dt = 0; dt < 4; ++dt) Oa[ht][dt][r] *= ar;
      }
    // P -> A-operand layout (hi/lo), quad shuffles
    bf16x8 ph[5], pl[5];
#pragma unroll
    for (int ht = 0; ht < 5; ++ht) {
      union { bf16_t e[8]; bf16x8 v; } uh, ul;
#pragma unroll
      for (int j = 0; j < 8; ++j) {
        const int src = (((2*q4 + (j>>2)) & 3) << 4) + c;
        const float v0 = __shfl(S[0][ht][j & 3], src);
        const float v1 = __shfl(S[1][ht][j & 3], src);
        const float val = (q4 < 2) ? v0 : v1;
        const bf16_t hi = (bf16_t)val;
        uh.e[j] = hi;
        ul.e[j] = (bf16_t)(val - (float)hi);
      }
      ph[ht] = uh.v;  pl[ht] = ul.v;
    }
    // V B-fragments: B[k=key][n=dim]
    bf16x8 vf[4];
#pragma unroll
    for (int dt = 0; dt < 4; ++dt) {
      union { bf16_t e[8]; bf16x8 v; } uv;
#pragma unroll
      for (int j = 0; j < 8; ++j)
        uv.e[j] = (bf16_t)vc[(kvbase + s0 + q4*8 + j)*HDc + dt*16 + c];
      vf[dt] = uv.v;
    }
#pragma unroll
    for (int ht = 0; ht < 5; ++ht)
#pragma unroll
      for (int dt = 0; dt < 4; ++dt) {
        Oa[ht][dt] = MFMA16(ph[ht], vf[dt], Oa[ht][dt]);
        Oa[ht][dt] = MFMA16(pl[ht], vf[dt], Oa[ht][dt]);
      }
  }

  // ---- block-level combine of the 4 wave segments ----
  if (lane < 16)
#pragma unroll
    for (int ht = 0; ht < 5; ++ht) {
      sM[wave][ht*16 + lane] = m_i[ht];
      sL[wave][ht*16 + lane] = l_i[ht];
    }
  __syncthreads();
#pragma unroll
  for (int ht = 0; ht < 5; ++ht)
#pragma unroll
    for (int r = 0; r < 4; ++r) {
      const int hh = ht*16 + q4*4 + r;
      float mg = fmaxf(fmaxf(sM[0][hh], sM[1][hh]), fmaxf(sM[2][hh], sM[3][hh]));
      mg = fmaxf(mg, -1e30f);
      const float aw = __expf(sM[wave][hh] - mg);
#pragma unroll
      for (int dt = 0; dt < 4; ++dt) Oa[ht][dt][r] *= aw;
    }
  for (int w = 0; w < 4; ++w) {
    if (wave == w) {
#pragma unroll
      for (int ht = 0; ht < 5; ++ht)
#pragma unroll
        for (int dt = 0; dt < 4; ++dt)
#pragma unroll
          for (int r = 0; r < 4; ++r) {
            const int idx = (ht*16 + q4*4 + r)*HDc + dt*16 + c;
            if (w == 0) sO[idx] = Oa[ht][dt][r];
            else        sO[idx] += Oa[ht][dt][r];
          }
    }
    __syncthreads();
  }
  float* op = Op + ((long)u*NPB + pb)*NHc*HDc;
  for (int i = tid; i < NHc*HDc; i += 256) op[i] = sO[i];
  if (wave == 0 && lane < 16) {
#pragma unroll
    for (int ht = 0; ht < 5; ++ht) {
      const int hh = ht*16 + lane;
      if (hh < NHc) {
        float mg = fmaxf(fmaxf(sM[0][hh], sM[1][hh]), fmaxf(sM[2][hh], sM[3][hh]));
        mg = fmaxf(mg, -1e30f);
        float L = 0.f;
#pragma unroll
        for (int w = 0; w < 4; ++w) L += __expf(sM[w][hh] - mg)*sL[w][hh];
        Mp[((long)u*NPB + pb)*NHc + hh] = mg;
        Lp[((long)u*NPB + pb)*NHc + hh] = L;
      }
    }
  }
}

// ---------------- Kernel 4: combine + current token, grid (71,32) ----------------
__global__ __launch_bounds__(64) void k_combine(
    const float* __restrict__ Mp, const float* __restrict__ Lp,
    const float* __restrict__ Op,
    const bf16_t* __restrict__ qhi, const bf16_t* __restrict__ qlo,
    const float* __restrict__ kcur, const float* __restrict__ vcur,
    bf16_t* __restrict__ ahi, bf16_t* __restrict__ alo, const int NPB)
{
  const int h = blockIdx.x, u = blockIdx.y;
  const int lane = threadIdx.x;   // = d
  const long qidx = ((long)u*NHPc + h)*HDc + lane;
  float pr = ((float)qhi[qidx] + (float)qlo[qidx]) * kcur[u*HDc + lane];
#pragma unroll
  for (int o = 32; o > 0; o >>= 1) pr += __shfl_xor(pr, o);
  const float s_cur = pr * 0.125f;

  float g = s_cur;
  for (int p = 0; p < NPB; ++p)
    g = fmaxf(g, Mp[((long)u*NPB + p)*NHc + h]);
  g = fmaxf(g, -1e30f);
  float sw = 0.f, acc = 0.f;
  const float* ob = Op + (long)u*NPB*NHc*HDc + (long)h*HDc + lane;
  for (int p = 0; p < NPB; ++p) {
    const float f = __expf(Mp[((long)u*NPB + p)*NHc + h] - g);
    sw += f*Lp[((long)u*NPB + p)*NHc + h];
    acc += f*ob[(long)p*NHc*HDc];
  }
  const float cw = __expf(s_cur - g);
  acc += cw * vcur[u*HDc + lane];
  const float attn = acc / (sw + cw);
  const bf16_t hi = (bf16_t)attn;
  ahi[(long)u*HIDc + h*HDc + lane] = hi;
  alo[(long)u*HIDc + h*HDc + lane] = (bf16_t)(attn - (float)hi);
}

// ---------------- Kernel 5: dense GEMM, grid (142,8), atomic reduce ----------------
__global__ __launch_bounds__(256) void k_outgemm(
    const bf16_t* __restrict__ ahi, const bf16_t* __restrict__ alo,
    const float* __restrict__ wd, float* __restrict__ out)
{
  const int nb = blockIdx.x, y = blockIdx.y;
  const int t = threadIdx.x;
  const int wave = t >> 6, lane = t & 63;
  const int c = lane & 15, q4 = lane >> 4;
  const int mt = wave & 1, kh = wave >> 1;
  const int ks0 = y*18;
  const int ksn = min(18, 142 - ks0);
  const int h1  = ksn >> 1;
  const int kbeg = ks0 + (kh ? h1 : 0);
  const int kend = ks0 + (kh ? ksn : h1);
  __shared__ float sC[Uc*32];

  const bf16_t* aph = ahi + ((long)(mt*16 + c))*HIDc + q4*8;
  const bf16_t* apl = alo + ((long)(mt*16 + c))*HIDc + q4*8;
  const long bbase = ((long)nb*32 + c)*HIDc + q4*8;

  f32x4 acc[2] = {};
#pragma unroll 3
  for (int ks = kbeg; ks < kend; ++ks) {
    const bf16x8 Ah = *(const bf16x8*)(aph + ks*32);
    const bf16x8 Al = *(const bf16x8*)(apl + ks*32);
#pragma unroll
    for (int nf = 0; nf < 2; ++nf) {
      const bf16x8 B = ld8f(wd, bbase + (long)nf*16*HIDc + ks*32);
      acc[nf] = MFMA16(Ah, B, acc[nf]);
      acc[nf] = MFMA16(Al, B, acc[nf]);
    }
  }
  if (kh == 0) {
#pragma unroll
    for (int r = 0; r < 4; ++r)
#pragma unroll
      for (int nf = 0; nf < 2; ++nf)
        sC[(mt*16 + q4*4 + r)*32 + nf*16 + c] = acc[nf][r];
  }
  __syncthreads();
  if (kh == 1) {
#pragma unroll
    for (int r = 0; r < 4; ++r)
#pragma unroll
      for (int nf = 0; nf < 2; ++nf)
        sC[(mt*16 + q4*4 + r)*32 + nf*16 + c] += acc[nf][r];
  }
  __syncthreads();
  for (int i = t; i < Uc*32; i += 256)
    atomicAdd(&out[(long)(i >> 5)*HIDc + nb*32 + (i & 31)], sC[i]);
}

extern "C" void kernel_launch(void* const* d_in, const int* in_sizes, int n_in,
                              void* d_out, int out_size, void* d_ws, size_t ws_size,
                              hipStream_t stream)
{
  const float* hidden = (const float*)d_in[0];
  const float* cosp   = (const float*)d_in[1];
  const float* sinp   = (const float*)d_in[2];
  const float* kcache = (const float*)d_in[3];
  const float* vcache = (const float*)d_in[4];
  const float* masks  = (const float*)d_in[5];
  const float* wqkv   = (const float*)d_in[6];
  const float* wdense = (const float*)d_in[7];
  float* out = (float*)d_out;

  // pick NPB (flash partials per user) by available workspace
  const size_t opb = (size_t)Uc*NHc*HDc*4;
  int NPB = 16;
  if      (ws_size >= OFF_OP + 16*opb) NPB = 16;
  else if (ws_size >= OFF_OP +  8*opb) NPB = 8;
  else if (ws_size >= OFF_OP +  4*opb) NPB = 4;
  else return;

  char* ws = (char*)d_ws;
  float*  fused = (float*)(ws + OFF_FUSED);
  bf16_t* qhi   = (bf16_t*)(ws + OFF_QHI);
  bf16_t* qlo   = (bf16_t*)(ws + OFF_QLO);
  float*  kcur  = (float*)(ws + OFF_KCUR);
  float*  vcur  = (float*)(ws + OFF_VCUR);
  float*  Mp    = (float*)(ws + OFF_MP);
  float*  Lp    = (float*)(ws + OFF_LP);
  bf16_t* ahi   = (bf16_t*)(ws + OFF_AHI);
  bf16_t* alo   = (bf16_t*)(ws + OFF_ALO);
  float*  Op    = (float*)(ws + OFF_OP);

  k_zeros  <<<1152, 256, 0, stream>>>(fused, out);
  k_qkv    <<<dim3(73, 8), 256, 0, stream>>>(hidden, wqkv, fused);
  k_rotary <<<80, 256, 0, stream>>>(fused, cosp, sinp, qhi, qlo, kcur, vcur);
  k_attn   <<<dim3(32, NPB), 256, 0, stream>>>(kcache, vcache, masks, qhi, qlo, Mp, Lp, Op, NPB);
  k_combine<<<dim3(71, 32), 64, 0, stream>>>(Mp, Lp, Op, qhi, qlo, kcur, vcur, ahi, alo, NPB);
  k_outgemm<<<dim3(142, 8), 256, 0, stream>>>(ahi, alo, wdense, out);
}